// Round 1
// baseline (22.494 us; speedup 1.0000x reference)
//
#include <hip/hip_runtime.h>

// CLUB loss, algebraically collapsed:
//   loss = -0.5/N * S_pos + 0.5/N^2 * ( dot(S_invv, S_x2) - 2*dot(S_muinvv, S_x) + N*S_c )
// where all S_* are sums over the N=16384 rows (d=64 columns).
//
// ws layout (doubles): [0:64) S_x | [64:128) S_x2 | [128:192) S_invv |
//                      [192:256) S_muinvv | [256] S_c | [257] S_pos

#define NROWS 16384
#define DDIM  64

__global__ __launch_bounds__(256) void club_pass1(const float* __restrict__ x,
                                                  const float* __restrict__ mu,
                                                  const float* __restrict__ logvar,
                                                  double* __restrict__ acc) {
    __shared__ float xt[64 * 65];     // x tile, padded stride 65 (conflict-free transpose read)
    __shared__ double red[256];

    const int tid = threadIdx.x;
    const int i0  = blockIdx.x * 64;          // first row of this block's tile
    const int b   = i0 >> 10;                 // 1024 rows per batch image (h*w = 32*32)
    const int hw0 = i0 & 1023;
    const float* xb = x + (size_t)b * 65536 + hw0;   // x[b, 0, hw0]

    // Stage x[b, d, hw0:hw0+64] for d=0..63 — coalesced 64-float rows.
    #pragma unroll
    for (int t = tid; t < 4096; t += 256) {
        const int dd = t >> 6, j = t & 63;
        xt[dd * 65 + j] = xb[(size_t)dd * 1024 + j];
    }
    __syncthreads();

    const int d  = tid & 63;   // lane -> column d (coalesced mu/logvar)
    const int j0 = tid >> 6;   // wave -> row sub-block

    double a_x = 0.0, a_x2 = 0.0, a_iv = 0.0, a_miv = 0.0, a_c = 0.0, a_pos = 0.0;

    #pragma unroll
    for (int k = 0; k < 16; ++k) {
        const int j = j0 * 16 + k;                       // wave-uniform row
        const float xv = xt[d * 65 + j];                 // 2-way bank access (free)
        const int idx  = (i0 + j) * DDIM + d;            // coalesced
        const float m  = mu[idx];
        const float lv = logvar[idx];
        const float iv = expf(-lv);
        const float t2 = xv - m;
        a_x   += (double)xv;
        a_x2  += (double)(xv * xv);
        a_iv  += (double)iv;
        a_miv += (double)(m * iv);
        a_c   += (double)(m * m * iv);
        a_pos += (double)(t2 * t2 * iv);
    }

    // Per-d vector reductions: 4 threads per d (tid, tid+64, tid+128, tid+192).
    #define VEC_REDUCE(val, base)                                                    \
        red[tid] = (val); __syncthreads();                                           \
        if (tid < 64) {                                                              \
            double s = red[tid] + red[tid + 64] + red[tid + 128] + red[tid + 192];   \
            atomicAdd(&acc[(base) + tid], s);                                        \
        }                                                                            \
        __syncthreads();

    VEC_REDUCE(a_x,   0)
    VEC_REDUCE(a_x2,  64)
    VEC_REDUCE(a_iv,  128)
    VEC_REDUCE(a_miv, 192)
    #undef VEC_REDUCE

    // Scalar reductions.
    red[tid] = a_c; __syncthreads();
    if (tid < 64) {
        double s = red[tid] + red[tid + 64] + red[tid + 128] + red[tid + 192];
        #pragma unroll
        for (int off = 32; off > 0; off >>= 1) s += __shfl_down(s, off, 64);
        if (tid == 0) atomicAdd(&acc[256], s);
    }
    __syncthreads();
    red[tid] = a_pos; __syncthreads();
    if (tid < 64) {
        double s = red[tid] + red[tid + 64] + red[tid + 128] + red[tid + 192];
        #pragma unroll
        for (int off = 32; off > 0; off >>= 1) s += __shfl_down(s, off, 64);
        if (tid == 0) atomicAdd(&acc[257], s);
    }
}

__global__ void club_finalize(const double* __restrict__ acc, float* __restrict__ out) {
    const int d = threadIdx.x;   // 64 threads
    double term = acc[128 + d] * acc[64 + d] - 2.0 * acc[192 + d] * acc[d];
    #pragma unroll
    for (int off = 32; off > 0; off >>= 1) term += __shfl_down(term, off, 64);
    if (d == 0) {
        const double Nd = (double)NROWS;
        const double sumD = term + Nd * acc[256];
        const double loss = -0.5 / Nd * acc[257] + 0.5 / (Nd * Nd) * sumD;
        out[0] = (float)loss;
    }
}

extern "C" void kernel_launch(void* const* d_in, const int* in_sizes, int n_in,
                              void* d_out, int out_size, void* d_ws, size_t ws_size,
                              hipStream_t stream) {
    const float* x      = (const float*)d_in[0];
    const float* mu     = (const float*)d_in[1];
    const float* logvar = (const float*)d_in[2];
    float* out  = (float*)d_out;
    double* acc = (double*)d_ws;

    hipMemsetAsync(acc, 0, 258 * sizeof(double), stream);
    club_pass1<<<NROWS / 64, 256, 0, stream>>>(x, mu, logvar, acc);
    club_finalize<<<1, 64, 0, stream>>>(acc, out);
}